// Round 15
// baseline (833.816 us; speedup 1.0000x reference)
//
#include <hip/hip_runtime.h>

#define DD   256    // feature dim
#define CC   100    // num classes
#define CAP  8192   // bucket capacity per class (multiple of 64; ~110 sigma margin)
#define WPC  (CAP / 64)        // 128 windows per class
#define TPB_ARG 192            // 3 waves
#define TILES_PER_BLK 16       // 1024 rows per argmax block

typedef float f4 __attribute__((ext_vector_type(4)));

// Workspace layout (bytes):
//   [0, 102400)        : g_sums   (CC*DD f32, natural layout)
//   [102400, 102800)   : g_counts (CC int)
//   [102800, 103200)   : g_cursor (CC int)
//   [103200, 103600)   : g_ssqc   (CC f32 — per-class sum of squares)
//   [103680, +CC*CAP*4): bucket   (row indices grouped by class)
#define WS_SUMS_OFF   0
#define WS_COUNTS_OFF (CC * DD * 4)
#define WS_CURSOR_OFF (WS_COUNTS_OFF + CC * 4)
#define WS_SSQC_OFF   (WS_CURSOR_OFF + CC * 4)
#define WS_HDR        (WS_SSQC_OFF + CC * 4)
#define WS_BUCKET_OFF 103680

// ---------------- kernel A: argmax + fused block-local rank/scatter ---------
// Per block: 1024-row slab, 16 tiles of 64 rows. Waves DMA label tiles into
// private double-buffered LDS (25x global_load_lds w16, counted vmcnt), lane
// argmaxes its row, records (row,cls) + LDS-atomic rank. After the slab: one
// global cursor atomic per (block,class), then rows written straight into
// per-class buckets. No separate scatter pass, no cls array.
__global__ __launch_bounds__(TPB_ARG) void k_argmax(
        const float* __restrict__ labels,
        const float* __restrict__ feats,       // overflow fallback only
        int*   __restrict__ bucket,
        int*   __restrict__ g_counts,
        int*   __restrict__ g_cursor,
        float* __restrict__ g_sums,            // overflow fallback only
        float* __restrict__ g_ssqc,            // overflow fallback only
        int N)
{
    __shared__ f4  stage[3][2][1600];          // 153600 B (3 waves x 2 x 25.6KB)
    __shared__ int s_pack[TILES_PER_BLK * 64]; // 4096 B : (row<<7)|cls
    __shared__ unsigned short s_rank[TILES_PER_BLK * 64]; // 2048 B
    __shared__ int s_hist[CC];                 // 400 B
    __shared__ int s_base[CC];                 // 400 B   (total ~160.5 KB)

    const int tid  = threadIdx.x;
    const int lane = tid & 63;
    const int wid  = tid >> 6;
    if (tid < CC) s_hist[tid] = 0;
    __syncthreads();

    const int ntiles = N >> 6;
    const int t0 = blockIdx.x * TILES_PER_BLK;

#define DMA(b_, t_) do {                                                      \
    const float* gbase = labels + (size_t)(t_) * 6400 + lane * 4;             \
    f4* lbase = &stage[wid][b_][0];                                           \
    _Pragma("unroll")                                                         \
    for (int i_ = 0; i_ < 25; ++i_)                                           \
        __builtin_amdgcn_global_load_lds(                                     \
            (const __attribute__((address_space(1))) unsigned int*)(gbase + i_ * 256), \
            (__attribute__((address_space(3))) unsigned int*)(lbase + i_ * 64),       \
            16, 0, 0);                                                        \
} while (0)

#define CONSUME(b_, t_, tl_) do {                                             \
    const f4* row_ = &stage[wid][b_][lane * 25];                              \
    f4 q0_ = row_[0];                                                         \
    float best_ = q0_[0]; int bi_ = 0;                                        \
    if (q0_[1] > best_) { best_ = q0_[1]; bi_ = 1; }                          \
    if (q0_[2] > best_) { best_ = q0_[2]; bi_ = 2; }                          \
    if (q0_[3] > best_) { best_ = q0_[3]; bi_ = 3; }                          \
    _Pragma("unroll")                                                         \
    for (int j_ = 1; j_ < 25; ++j_) {                                         \
        f4 q_ = row_[j_];                                                     \
        if (q_[0] > best_) { best_ = q_[0]; bi_ = 4 * j_; }                   \
        if (q_[1] > best_) { best_ = q_[1]; bi_ = 4 * j_ + 1; }               \
        if (q_[2] > best_) { best_ = q_[2]; bi_ = 4 * j_ + 2; }               \
        if (q_[3] > best_) { best_ = q_[3]; bi_ = 4 * j_ + 3; }               \
    }                                                                         \
    const int li_ = (tl_) * 64 + lane;                                        \
    s_pack[li_] = (int)((((unsigned)((t_) * 64 + lane)) << 7) | (unsigned)bi_); \
    s_rank[li_] = (unsigned short)atomicAdd(&s_hist[bi_], 1);                 \
} while (0)

    int tl = wid;
    if (tl < TILES_PER_BLK && t0 + tl < ntiles) {
        DMA(0, t0 + tl);
        int cur = 0;
        int tln = tl + 3;
        while (tln < TILES_PER_BLK && t0 + tln < ntiles) {
            DMA(cur ^ 1, t0 + tln);                        // prefetch next tile
            asm volatile("s_waitcnt vmcnt(25)" ::: "memory");
            __builtin_amdgcn_sched_barrier(0);
            CONSUME(cur, t0 + tl, tl);
            cur ^= 1; tl = tln; tln += 3;
        }
        asm volatile("s_waitcnt vmcnt(0)" ::: "memory");
        __builtin_amdgcn_sched_barrier(0);
        CONSUME(cur, t0 + tl, tl);
    }
#undef DMA
#undef CONSUME

    // tail rows (N % 64 != 0): last block, wave 0, direct slow path
    if (blockIdx.x == gridDim.x - 1 && wid == 0) {
        const int row = (ntiles << 6) + lane;
        if (row < N) {
            const float* lr = labels + (size_t)row * CC;
            float best = lr[0]; int bi = 0;
            for (int j = 1; j < CC; ++j)
                if (lr[j] > best) { best = lr[j]; bi = j; }
            const int pos = atomicAdd(&g_cursor[bi], 1);
            atomicAdd(&g_counts[bi], 1);
            if (pos < CAP) bucket[bi * CAP + pos] = row;
            // (overflow impossible here in practice; rows would be handled below)
        }
    }

    __syncthreads();                            // all slab rows classified

    // one global cursor/count atomic per (block, class)
    if (tid < CC) {
        const int h = s_hist[tid];
        if (h > 0) {
            s_base[tid] = atomicAdd(&g_cursor[tid], h);
            atomicAdd(&g_counts[tid], h);
        }
    }
    __syncthreads();

    // write rows into buckets
    const int tiles_here = min(TILES_PER_BLK, ntiles - t0);
    const int nrows = (tiles_here > 0) ? tiles_here * 64 : 0;
    for (int i = tid; i < nrows; i += TPB_ARG) {
        const int pk  = s_pack[i];
        const int c   = pk & 127;
        const int row = (int)(((unsigned)pk) >> 7);
        const int pos = s_base[c] + (int)s_rank[i];
        if (pos < CAP) {
            bucket[c * CAP + pos] = row;
        } else {
            // overflow fallback (never taken at CAP=8192): accumulate directly
            const f4* fr = (const f4*)(feats + (size_t)row * DD);
            float ss = 0.f;
            for (int j = 0; j < 64; ++j) {
                f4 v = fr[j];
                unsafeAtomicAdd(&g_sums[c * DD + j * 4 + 0], v[0]);
                unsafeAtomicAdd(&g_sums[c * DD + j * 4 + 1], v[1]);
                unsafeAtomicAdd(&g_sums[c * DD + j * 4 + 2], v[2]);
                unsafeAtomicAdd(&g_sums[c * DD + j * 4 + 3], v[3]);
                ss += v[0]*v[0] + v[1]*v[1] + v[2]*v[2] + v[3]*v[3];
            }
            unsafeAtomicAdd(&g_ssqc[c], ss);
        }
    }
}

// ---------------- kernel B: bucketed streaming accumulate -------------------
// One wave = one 64-slot window of ONE class (wave-uniform, constant):
// zero class logic, readlane-with-immediate row indices -> SGPR-base loads,
// 4-deep named pipeline, single register accumulator, ONE flush per wave.
__global__ __launch_bounds__(256, 4) void k_accum(
        const float* __restrict__ feats,
        const int*   __restrict__ bucket,
        const int*   __restrict__ g_counts,
        float* __restrict__ g_sums,
        float* __restrict__ g_ssqc)
{
    const int tid  = threadIdx.x;
    const int lane = tid & 63;
    const int wid  = tid >> 6;
    const int cls  = blockIdx.x >> 5;            // 32 blocks per class (WPC/4)
    const int win  = ((blockIdx.x & 31) << 2) + wid;
    const int local0 = win << 6;

    int cnt = g_counts[cls];
    if (cnt > CAP) cnt = CAP;                    // overflow rows handled in k_argmax
    const int nv = cnt - local0;
    if (nv <= 0) return;                         // idle wave (no barrier below)

    const int slot  = local0 + ((lane < nv) ? lane : 0);
    const int ord64 = bucket[cls * CAP + slot];  // coalesced; lanes>=nv unused

    const f4* feats4 = (const f4*)feats;
    f4    acc = {0.f, 0.f, 0.f, 0.f};
    float ssq = 0.f;
    f4 fA[4], fB[4], fC[4], fD[4];

#define LOADB(F_, B_)                                                         \
    _Pragma("unroll")                                                         \
    for (int r_ = 0; r_ < 4; ++r_) {                                          \
        if ((B_) * 4 + r_ < nv) {                                             \
            const int rw_ = __builtin_amdgcn_readlane(ord64, (B_) * 4 + r_);  \
            F_[r_] = feats4[((size_t)rw_ << 6) + lane];                       \
        }                                                                     \
    }

#define PROCB(F_, B_)                                                         \
    _Pragma("unroll")                                                         \
    for (int r_ = 0; r_ < 4; ++r_) {                                          \
        if ((B_) * 4 + r_ < nv) {                                             \
            acc += F_[r_];                                                    \
            ssq += F_[r_][0] * F_[r_][0] + F_[r_][1] * F_[r_][1]              \
                 + F_[r_][2] * F_[r_][2] + F_[r_][3] * F_[r_][3];             \
        }                                                                     \
    }

    LOADB(fA, 0); LOADB(fB, 1); LOADB(fC, 2); LOADB(fD, 3);
    PROCB(fA, 0);  LOADB(fA, 4);
    PROCB(fB, 1);  LOADB(fB, 5);
    PROCB(fC, 2);  LOADB(fC, 6);
    PROCB(fD, 3);  LOADB(fD, 7);
    PROCB(fA, 4);  LOADB(fA, 8);
    PROCB(fB, 5);  LOADB(fB, 9);
    PROCB(fC, 6);  LOADB(fC, 10);
    PROCB(fD, 7);  LOADB(fD, 11);
    PROCB(fA, 8);  LOADB(fA, 12);
    PROCB(fB, 9);  LOADB(fB, 13);
    PROCB(fC, 10); LOADB(fC, 14);
    PROCB(fD, 11); LOADB(fD, 15);
    PROCB(fA, 12); PROCB(fB, 13); PROCB(fC, 14); PROCB(fD, 15);
#undef LOADB
#undef PROCB

    // single flush per wave: class is constant for the whole window
    float* dst = g_sums + (size_t)cls * DD + lane * 4;
    unsafeAtomicAdd(dst + 0, acc[0]);
    unsafeAtomicAdd(dst + 1, acc[1]);
    unsafeAtomicAdd(dst + 2, acc[2]);
    unsafeAtomicAdd(dst + 3, acc[3]);

    // sumsq: wave reduce -> one fire-and-forget f32 atomic per wave
    #pragma unroll
    for (int off = 1; off < 64; off <<= 1) ssq += __shfl_xor(ssq, off);
    if (lane == 0) unsafeAtomicAdd(&g_ssqc[cls], ssq);
}

// ---------------- finalize ---------------------------------------------------
__global__ __launch_bounds__(DD) void affinity_finalize(
        const float* __restrict__ g_sums,
        const int*   __restrict__ g_counts,
        const float* __restrict__ g_ssqc,
        float* __restrict__ out)
{
    const int d = threadIdx.x;
    __shared__ int s_cnt[CC];
    if (d < CC) s_cnt[d] = g_counts[d];
    __syncthreads();

    double colsum = 0.0, s2 = 0.0, dot = 0.0, cc = 0.0;
    for (int cb = 0; cb < CC; cb += 4) {         // CC % 4 == 0
        float s[4];
        #pragma unroll
        for (int k = 0; k < 4; ++k)              // 4 independent loads in flight
            s[k] = g_sums[(size_t)(cb + k) * DD + d];
        #pragma unroll
        for (int k = 0; k < 4; ++k) {
            const int    cnt = s_cnt[cb + k];
            const double center = (cnt > 0 ? (double)s[k] / (double)cnt : 0.0) + 1e-6;
            colsum += center;
            s2     += center * center;
            dot    += center * (double)s[k];
            cc     += (double)cnt * center * center;
        }
    }
    double interp = s2 - colsum * colsum / (double)CC;

    __shared__ double red0[DD], red1[DD], red2[DD], red3[DD];
    red0[d] = dot; red1[d] = cc; red2[d] = interp;
    red3[d] = (d < CC) ? (double)g_ssqc[d] : 0.0;
    __syncthreads();
    for (int off = DD / 2; off > 0; off >>= 1) {
        if (d < off) {
            red0[d] += red0[d + off];
            red1[d] += red1[d + off];
            red2[d] += red2[d + off];
            red3[d] += red3[d + off];
        }
        __syncthreads();
    }
    if (d == 0) {
        const double intra = red3[0] - 2.0 * red0[0] + red1[0];
        const double inter = red2[0] / (double)CC;
        out[0] = (float)(intra / (inter + 1e-6));
    }
}

extern "C" void kernel_launch(void* const* d_in, const int* in_sizes, int n_in,
                              void* d_out, int out_size, void* d_ws, size_t ws_size,
                              hipStream_t stream)
{
    const float* feats  = (const float*)d_in[0];
    const float* labels = (const float*)d_in[1];
    const int N = in_sizes[0] / DD;

    float* g_sums   = (float*)((char*)d_ws + WS_SUMS_OFF);
    int*   g_counts = (int*)((char*)d_ws + WS_COUNTS_OFF);
    int*   g_cursor = (int*)((char*)d_ws + WS_CURSOR_OFF);
    float* g_ssqc   = (float*)((char*)d_ws + WS_SSQC_OFF);
    int*   bucket   = (int*)((char*)d_ws + WS_BUCKET_OFF);

    hipMemsetAsync(d_ws, 0, WS_HDR, stream);     // zero sums/counts/cursor/ssqc

    const int ntiles = N >> 6;
    int nbA = (ntiles + TILES_PER_BLK - 1) / TILES_PER_BLK;
    if (nbA < 1) nbA = 1;
    k_argmax<<<nbA, TPB_ARG, 0, stream>>>(labels, feats, bucket, g_counts,
                                          g_cursor, g_sums, g_ssqc, N);

    k_accum<<<CC * (WPC / 4), 256, 0, stream>>>(feats, bucket, g_counts,
                                                g_sums, g_ssqc);

    affinity_finalize<<<1, DD, 0, stream>>>(g_sums, g_counts, g_ssqc,
                                            (float*)d_out);
}

// Round 16
// 113.294 us; speedup vs baseline: 7.3598x; 7.3598x over previous
//
#include <hip/hip_runtime.h>

#define DD   256    // feature dim
#define CC   100    // num classes
#define CAP  4096   // bucket capacity per class (multiple of 64; ~29 sigma margin)
#define WPC  (CAP / 64)        // 64 windows per class
#define TPB_ARG 192            // 3 waves
#define TILES_PER_BLK 16       // 1024 rows per argmax block

typedef float f4 __attribute__((ext_vector_type(4)));

// Workspace layout (bytes):
//   [0, 102400)        : g_sums   (CC*DD f32, natural layout)
//   [102400, 102800)   : g_counts (CC int)
//   [102800, 103200)   : g_cursor (CC int)
//   [103200, 103600)   : g_ssqc   (CC f32 — per-class sum of squares)
//   [103680, +CC*CAP*4): bucket   (row indices grouped by class)
#define WS_SUMS_OFF   0
#define WS_COUNTS_OFF (CC * DD * 4)
#define WS_CURSOR_OFF (WS_COUNTS_OFF + CC * 4)
#define WS_SSQC_OFF   (WS_CURSOR_OFF + CC * 4)
#define WS_HDR        (WS_SSQC_OFF + CC * 4)
#define WS_BUCKET_OFF 103680

// ---------------- kernel A: argmax + fused block-local rank/scatter ---------
// (unchanged from round 15 — measured ~20 µs incl. finalize) Per block:
// 1024-row slab, 16 tiles of 64 rows, wave-private double-buffered LDS DMA
// (25x global_load_lds w16, counted vmcnt), per-lane argmax, LDS rank, one
// cursor atomic per (block,class), rows written straight into class buckets.
__global__ __launch_bounds__(TPB_ARG) void k_argmax(
        const float* __restrict__ labels,
        const float* __restrict__ feats,       // overflow fallback only
        int*   __restrict__ bucket,
        int*   __restrict__ g_counts,
        int*   __restrict__ g_cursor,
        float* __restrict__ g_sums,            // overflow fallback only
        float* __restrict__ g_ssqc,            // overflow fallback only
        int N)
{
    __shared__ f4  stage[3][2][1600];          // 153600 B (3 waves x 2 x 25.6KB)
    __shared__ int s_pack[TILES_PER_BLK * 64]; // 4096 B : (row<<7)|cls
    __shared__ unsigned short s_rank[TILES_PER_BLK * 64]; // 2048 B
    __shared__ int s_hist[CC];                 // 400 B
    __shared__ int s_base[CC];                 // 400 B   (total ~156.8 KB)

    const int tid  = threadIdx.x;
    const int lane = tid & 63;
    const int wid  = tid >> 6;
    if (tid < CC) s_hist[tid] = 0;
    __syncthreads();

    const int ntiles = N >> 6;
    const int t0 = blockIdx.x * TILES_PER_BLK;

#define DMA(b_, t_) do {                                                      \
    const float* gbase = labels + (size_t)(t_) * 6400 + lane * 4;             \
    f4* lbase = &stage[wid][b_][0];                                           \
    _Pragma("unroll")                                                         \
    for (int i_ = 0; i_ < 25; ++i_)                                           \
        __builtin_amdgcn_global_load_lds(                                     \
            (const __attribute__((address_space(1))) unsigned int*)(gbase + i_ * 256), \
            (__attribute__((address_space(3))) unsigned int*)(lbase + i_ * 64),       \
            16, 0, 0);                                                        \
} while (0)

#define CONSUME(b_, t_, tl_) do {                                             \
    const f4* row_ = &stage[wid][b_][lane * 25];                              \
    f4 q0_ = row_[0];                                                         \
    float best_ = q0_[0]; int bi_ = 0;                                        \
    if (q0_[1] > best_) { best_ = q0_[1]; bi_ = 1; }                          \
    if (q0_[2] > best_) { best_ = q0_[2]; bi_ = 2; }                          \
    if (q0_[3] > best_) { best_ = q0_[3]; bi_ = 3; }                          \
    _Pragma("unroll")                                                         \
    for (int j_ = 1; j_ < 25; ++j_) {                                         \
        f4 q_ = row_[j_];                                                     \
        if (q_[0] > best_) { best_ = q_[0]; bi_ = 4 * j_; }                   \
        if (q_[1] > best_) { best_ = q_[1]; bi_ = 4 * j_ + 1; }               \
        if (q_[2] > best_) { best_ = q_[2]; bi_ = 4 * j_ + 2; }               \
        if (q_[3] > best_) { best_ = q_[3]; bi_ = 4 * j_ + 3; }               \
    }                                                                         \
    const int li_ = (tl_) * 64 + lane;                                        \
    s_pack[li_] = (int)((((unsigned)((t_) * 64 + lane)) << 7) | (unsigned)bi_); \
    s_rank[li_] = (unsigned short)atomicAdd(&s_hist[bi_], 1);                 \
} while (0)

    int tl = wid;
    if (tl < TILES_PER_BLK && t0 + tl < ntiles) {
        DMA(0, t0 + tl);
        int cur = 0;
        int tln = tl + 3;
        while (tln < TILES_PER_BLK && t0 + tln < ntiles) {
            DMA(cur ^ 1, t0 + tln);                        // prefetch next tile
            asm volatile("s_waitcnt vmcnt(25)" ::: "memory");
            __builtin_amdgcn_sched_barrier(0);
            CONSUME(cur, t0 + tl, tl);
            cur ^= 1; tl = tln; tln += 3;
        }
        asm volatile("s_waitcnt vmcnt(0)" ::: "memory");
        __builtin_amdgcn_sched_barrier(0);
        CONSUME(cur, t0 + tl, tl);
    }
#undef DMA
#undef CONSUME

    // tail rows (N % 64 != 0): last block, wave 0, direct slow path
    if (blockIdx.x == gridDim.x - 1 && wid == 0) {
        const int row = (ntiles << 6) + lane;
        if (row < N) {
            const float* lr = labels + (size_t)row * CC;
            float best = lr[0]; int bi = 0;
            for (int j = 1; j < CC; ++j)
                if (lr[j] > best) { best = lr[j]; bi = j; }
            const int pos = atomicAdd(&g_cursor[bi], 1);
            atomicAdd(&g_counts[bi], 1);
            if (pos < CAP) bucket[bi * CAP + pos] = row;
        }
    }

    __syncthreads();                            // all slab rows classified

    // one global cursor/count atomic per (block, class)
    if (tid < CC) {
        const int h = s_hist[tid];
        if (h > 0) {
            s_base[tid] = atomicAdd(&g_cursor[tid], h);
            atomicAdd(&g_counts[tid], h);
        }
    }
    __syncthreads();

    // write rows into buckets
    const int tiles_here = min(TILES_PER_BLK, ntiles - t0);
    const int nrows = (tiles_here > 0) ? tiles_here * 64 : 0;
    for (int i = tid; i < nrows; i += TPB_ARG) {
        const int pk  = s_pack[i];
        const int c   = pk & 127;
        const int row = (int)(((unsigned)pk) >> 7);
        const int pos = s_base[c] + (int)s_rank[i];
        if (pos < CAP) {
            bucket[c * CAP + pos] = row;
        } else {
            // overflow fallback (~29 sigma; never taken): accumulate directly
            const f4* fr = (const f4*)(feats + (size_t)row * DD);
            float ss = 0.f;
            for (int j = 0; j < 64; ++j) {
                f4 v = fr[j];
                unsafeAtomicAdd(&g_sums[c * DD + j * 4 + 0], v[0]);
                unsafeAtomicAdd(&g_sums[c * DD + j * 4 + 1], v[1]);
                unsafeAtomicAdd(&g_sums[c * DD + j * 4 + 2], v[2]);
                unsafeAtomicAdd(&g_sums[c * DD + j * 4 + 3], v[3]);
                ss += v[0]*v[0] + v[1]*v[1] + v[2]*v[2] + v[3]*v[3];
            }
            unsafeAtomicAdd(&g_ssqc[c], ss);
        }
    }
}

// ---------------- kernel B: bucketed streaming accumulate -------------------
// One wave = one 64-slot window of ONE class. NO launch-bounds reg cap (r15
// spilled: VGPR pinned to 64 -> 587 MB scratch writes). Loads UNCONDITIONAL:
// lanes >= nv hold a clamped duplicate slot, so every readlane yields a valid
// row; only the accumulate keeps the (scalar, uniform) nv guard. 16 batches
// x 4 rows named-pipelined -> 16 KB in flight/wave, ~96 VGPR, no spill.
__global__ __launch_bounds__(256) void k_accum(
        const float* __restrict__ feats,
        const int*   __restrict__ bucket,
        const int*   __restrict__ g_counts,
        float* __restrict__ g_sums,
        float* __restrict__ g_ssqc)
{
    const int tid  = threadIdx.x;
    const int lane = tid & 63;
    const int wid  = tid >> 6;
    const int cls  = blockIdx.x >> 4;            // 16 blocks per class (WPC/4)
    const int win  = ((blockIdx.x & 15) << 2) + wid;
    const int local0 = win << 6;

    int cnt = g_counts[cls];
    if (cnt > CAP) cnt = CAP;                    // overflow rows done in k_argmax
    const int nv = cnt - local0;                 // valid rows in this window
    if (nv <= 0) return;                         // idle wave (no barriers below)

    const int slot  = local0 + ((lane < nv) ? lane : 0);   // clamp -> valid dup
    const int ord64 = bucket[cls * CAP + slot];  // coalesced

    const f4* feats4 = (const f4*)feats;
    f4    acc = {0.f, 0.f, 0.f, 0.f};
    float ssq = 0.f;
    f4 fA[4], fB[4], fC[4], fD[4];

#define LOADB(F_, B_)                                                         \
    _Pragma("unroll")                                                         \
    for (int r_ = 0; r_ < 4; ++r_) {                                          \
        const int rw_ = __builtin_amdgcn_readlane(ord64, (B_) * 4 + r_);      \
        F_[r_] = feats4[((size_t)rw_ << 6) + lane];   /* always valid row */  \
    }

#define PROCB(F_, B_)                                                         \
    _Pragma("unroll")                                                         \
    for (int r_ = 0; r_ < 4; ++r_) {                                          \
        if ((B_) * 4 + r_ < nv) {            /* scalar, uniform */            \
            acc += F_[r_];                                                    \
            ssq += F_[r_][0] * F_[r_][0] + F_[r_][1] * F_[r_][1]              \
                 + F_[r_][2] * F_[r_][2] + F_[r_][3] * F_[r_][3];             \
        }                                                                     \
    }

    LOADB(fA, 0); LOADB(fB, 1); LOADB(fC, 2); LOADB(fD, 3);
    PROCB(fA, 0);  LOADB(fA, 4);
    PROCB(fB, 1);  LOADB(fB, 5);
    PROCB(fC, 2);  LOADB(fC, 6);
    PROCB(fD, 3);  LOADB(fD, 7);
    PROCB(fA, 4);  LOADB(fA, 8);
    PROCB(fB, 5);  LOADB(fB, 9);
    PROCB(fC, 6);  LOADB(fC, 10);
    PROCB(fD, 7);  LOADB(fD, 11);
    PROCB(fA, 8);  LOADB(fA, 12);
    PROCB(fB, 9);  LOADB(fB, 13);
    PROCB(fC, 10); LOADB(fC, 14);
    PROCB(fD, 11); LOADB(fD, 15);
    PROCB(fA, 12); PROCB(fB, 13); PROCB(fC, 14); PROCB(fD, 15);
#undef LOADB
#undef PROCB

    // single flush per wave: class is constant for the whole window
    float* dst = g_sums + (size_t)cls * DD + lane * 4;
    unsafeAtomicAdd(dst + 0, acc[0]);
    unsafeAtomicAdd(dst + 1, acc[1]);
    unsafeAtomicAdd(dst + 2, acc[2]);
    unsafeAtomicAdd(dst + 3, acc[3]);

    // sumsq: wave reduce -> one fire-and-forget f32 atomic per wave
    #pragma unroll
    for (int off = 1; off < 64; off <<= 1) ssq += __shfl_xor(ssq, off);
    if (lane == 0) unsafeAtomicAdd(&g_ssqc[cls], ssq);
}

// ---------------- finalize ---------------------------------------------------
__global__ __launch_bounds__(DD) void affinity_finalize(
        const float* __restrict__ g_sums,
        const int*   __restrict__ g_counts,
        const float* __restrict__ g_ssqc,
        float* __restrict__ out)
{
    const int d = threadIdx.x;
    __shared__ int s_cnt[CC];
    if (d < CC) s_cnt[d] = g_counts[d];
    __syncthreads();

    double colsum = 0.0, s2 = 0.0, dot = 0.0, cc = 0.0;
    for (int cb = 0; cb < CC; cb += 4) {         // CC % 4 == 0
        float s[4];
        #pragma unroll
        for (int k = 0; k < 4; ++k)              // 4 independent loads in flight
            s[k] = g_sums[(size_t)(cb + k) * DD + d];
        #pragma unroll
        for (int k = 0; k < 4; ++k) {
            const int    cnt = s_cnt[cb + k];
            const double center = (cnt > 0 ? (double)s[k] / (double)cnt : 0.0) + 1e-6;
            colsum += center;
            s2     += center * center;
            dot    += center * (double)s[k];
            cc     += (double)cnt * center * center;
        }
    }
    double interp = s2 - colsum * colsum / (double)CC;

    __shared__ double red0[DD], red1[DD], red2[DD], red3[DD];
    red0[d] = dot; red1[d] = cc; red2[d] = interp;
    red3[d] = (d < CC) ? (double)g_ssqc[d] : 0.0;
    __syncthreads();
    for (int off = DD / 2; off > 0; off >>= 1) {
        if (d < off) {
            red0[d] += red0[d + off];
            red1[d] += red1[d + off];
            red2[d] += red2[d + off];
            red3[d] += red3[d + off];
        }
        __syncthreads();
    }
    if (d == 0) {
        const double intra = red3[0] - 2.0 * red0[0] + red1[0];
        const double inter = red2[0] / (double)CC;
        out[0] = (float)(intra / (inter + 1e-6));
    }
}

extern "C" void kernel_launch(void* const* d_in, const int* in_sizes, int n_in,
                              void* d_out, int out_size, void* d_ws, size_t ws_size,
                              hipStream_t stream)
{
    const float* feats  = (const float*)d_in[0];
    const float* labels = (const float*)d_in[1];
    const int N = in_sizes[0] / DD;

    float* g_sums   = (float*)((char*)d_ws + WS_SUMS_OFF);
    int*   g_counts = (int*)((char*)d_ws + WS_COUNTS_OFF);
    int*   g_cursor = (int*)((char*)d_ws + WS_CURSOR_OFF);
    float* g_ssqc   = (float*)((char*)d_ws + WS_SSQC_OFF);
    int*   bucket   = (int*)((char*)d_ws + WS_BUCKET_OFF);

    hipMemsetAsync(d_ws, 0, WS_HDR, stream);     // zero sums/counts/cursor/ssqc

    const int ntiles = N >> 6;
    int nbA = (ntiles + TILES_PER_BLK - 1) / TILES_PER_BLK;
    if (nbA < 1) nbA = 1;
    k_argmax<<<nbA, TPB_ARG, 0, stream>>>(labels, feats, bucket, g_counts,
                                          g_cursor, g_sums, g_ssqc, N);

    k_accum<<<CC * (WPC / 4), 256, 0, stream>>>(feats, bucket, g_counts,
                                                g_sums, g_ssqc);

    affinity_finalize<<<1, DD, 0, stream>>>(g_sums, g_counts, g_ssqc,
                                            (float*)d_out);
}